// Round 12
// baseline (166.298 us; speedup 1.0000x reference)
//
#include <hip/hip_runtime.h>
#include <cstdint>

#define NB    32
#define NTOK  1024
#define D_    768
#define NHR   4096
#define HID   384
#define KSEL  154
#define MSEL  4928          // 32*154 = 77 * 64
#define MT_   77            // m-tiles of 64
#define FLAT  3072

typedef short  s16x8 __attribute__((ext_vector_type(8)));
typedef unsigned short u16x8 __attribute__((ext_vector_type(8)));
typedef unsigned short u16x4 __attribute__((ext_vector_type(4)));
typedef float  f32x4 __attribute__((ext_vector_type(4)));

__device__ inline unsigned short f2bf(float f) {
    uint32_t u = __builtin_bit_cast(uint32_t, f);
    u += 0x7FFFu + ((u >> 16) & 1u);          // RNE
    return (unsigned short)(u >> 16);
}
__device__ inline float bf2f(unsigned short h) {
    uint32_t u = ((uint32_t)h) << 16;
    return __builtin_bit_cast(float, u);
}
__device__ inline s16x8 cvt8(const float* __restrict__ p) {
    float4 v0 = *(const float4*)p, v1 = *(const float4*)(p + 4);
    s16x8 r;
    r[0]=(short)f2bf(v0.x); r[1]=(short)f2bf(v0.y); r[2]=(short)f2bf(v0.z); r[3]=(short)f2bf(v0.w);
    r[4]=(short)f2bf(v1.x); r[5]=(short)f2bf(v1.y); r[6]=(short)f2bf(v1.z); r[7]=(short)f2bf(v1.w);
    return r;
}

// ---- workspace layout (bytes) ----
#define OFF_SEL   0              // int[4928]
#define OFF_RMAP  32768          // int[32768]        131072
#define OFF_GPART 163840         // f32 [4928][12]    236544
#define OFF_W1T   401408         // bf16 [384][3072]  2359296
#define OFF_W2T   2760704        // bf16 [768][384]    589824
#define OFF_WG1T  3350528        // bf16 [384][1536]  1179648
#define OFF_ABASE 4530176        // bf16 [4928][768]  7569408
#define OFF_H     12099584       // bf16 [4928][384]  3784704
#define OFF_RL    15884288       // bf16 [4928][768]  7569408
#define OFF_WF    23453696       // bf16 [384][384]    294912   Wfused_t[n][hh]
#define OFF_BC    23748608       // f32 [384]            1536   bg1 + b2@Wg1b
// ---- d_out scratch: Aloc bf16[4928][3072] at 0; P0..P2 f32[4928][384] after.
#define DOUT_P0   32505856
#define PSTRIDE   (MSEL * HID)

// ---------------- prep: blocks 0-31 topk, blocks 32+ weight transpose+cvt ----------------
__global__ __launch_bounds__(1024) void prep_kernel(
    const float* __restrict__ scores, int* __restrict__ sel, int* __restrict__ rmap,
    const float* __restrict__ W1, const float* __restrict__ W2, const float* __restrict__ Wg1,
    unsigned short* __restrict__ W1t, unsigned short* __restrict__ W2t,
    unsigned short* __restrict__ Wg1t)
{
    __shared__ float s[NTOK];
    __shared__ int cnt;
    __shared__ unsigned short T[4][64][66];
    const int bid = blockIdx.x;
    if (bid < NB) {
        const int b = bid;
        const int t = threadIdx.x;
        s[t] = scores[b * NTOK + t];
        if (t == 0) cnt = 0;
        __syncthreads();
        float v = s[t];
        int rank = 0;
        for (int j = 0; j < NTOK; ++j) {
            float vj = s[j];
            rank += (vj > v) || (vj == v && j < t);
        }
        int rm = -1;
        if (rank < KSEL) {
            int pos = atomicAdd(&cnt, 1);
            rm = b * KSEL + pos;
            sel[rm] = t;
        }
        rmap[b * NTOK + t] = rm;
    } else {
        const int g = threadIdx.x >> 8;
        const int tid = threadIdx.x & 255;
        const int tile = (bid - NB) * 4 + g;     // 0..503
        const float* src; unsigned short* dst; int K, N, kt, nt;
        if (tile < 288)      { src = W1;  dst = W1t;  K = FLAT; N = HID; nt = tile % 6;  kt = tile / 6;  }
        else if (tile < 360) { int l = tile - 288; src = W2;  dst = W2t;  K = HID;  N = D_;  nt = l % 12; kt = l / 12; }
        else                 { int l = tile - 360; src = Wg1; dst = Wg1t; K = 1536; N = HID; nt = l % 6;  kt = l / 6;  }
        const int k0 = kt * 64, n0 = nt * 64;
        {
            const int ln = tid & 63, kc = tid >> 6;
            #pragma unroll
            for (int j = 0; j < 16; ++j)
                T[g][ln][kc * 16 + j] = f2bf(src[(uint64_t)(k0 + kc * 16 + j) * N + n0 + ln]);
        }
        __syncthreads();
        {
            const int row = tid >> 2, c0 = (tid & 3) * 16;
            u16x8 v0, v1;
            #pragma unroll
            for (int p = 0; p < 8; ++p) { v0[p] = T[g][row][c0 + p]; v1[p] = T[g][row][c0 + 8 + p]; }
            *(u16x8*)(dst + (uint64_t)(n0 + row) * K + k0 + c0) = v0;
            *(u16x8*)(dst + (uint64_t)(n0 + row) * K + k0 + c0 + 8) = v1;
        }
    }
}

// ================= shared MFMA GEMM body =================
// MODE 0: BM=64,BN=128, split-K=3 (KLEN=1024): P[split] = Aloc @ W1t (f32 partials)
// MODE 1: BM=64,BN=128: rl = h @ W2t + b2 (bf16)
// MODE 2: BM=64,BN=64, K=1152: gate partials from SiLU([Abase|h] @ [Wg1a|Wfused]
//         + bias_comb + score*Wg1[1536]) dotted with Wg2
// MODE 3: BM=64,BN=64, K=768: Wfused_t[n][hh] = (Wg1t[:,768:]) x (W2 f32) -> bf16
template <int MODE>
__device__ __forceinline__ void gemm_body(
    int lin,
    const unsigned short* __restrict__ A0,   // m0: Aloc; m1: h; m2: Abase; m3: Wg1t+768
    const unsigned short* __restrict__ A1,   // m2: h
    const unsigned short* __restrict__ B0,   // m0: W1t; m1: W2t; m2: Wg1t
    const unsigned short* __restrict__ B1,   // m2: Wfused_t
    const float* __restrict__ Braw,          // m3: W2 (f32)
    const float* __restrict__ bias,          // m1: b2; m2: bias_comb
    const int* __restrict__ sel,
    const float* __restrict__ scores,
    const float* __restrict__ WgLast,
    const float* __restrict__ Wg2,
    void* __restrict__ Cout,
    float* __restrict__ Pout,
    float* __restrict__ gpart,
    unsigned short* __restrict__ AsS,        // 2 * 4096 bf16
    unsigned short* __restrict__ BsS,        // 2 * (BN*64) bf16
    float* __restrict__ scv)                 // 64 f32 (mode 2)
{
    constexpr int BN    = (MODE == 0 || MODE == 1) ? 128 : 64;
    constexpr int NFRAG = BN / 32;
    constexpr int N     = (MODE == 1) ? D_ : HID;
    constexpr int NT    = N / BN;            // m0:3 m1:6 m2:6 m3:6
    constexpr int KLEN  = (MODE == 0) ? 1024 : (MODE == 1) ? HID : (MODE == 2) ? 1152 : D_;
    constexpr int NSTEP = KLEN / 64;

    int mt, ntile, split;
    if constexpr (MODE == 3) {
        mt = lin / 6; ntile = lin % 6; split = 0;
    } else {
        const int xcd = lin & 7;             // XCD-grouping: same m-tile -> same XCD
        int j = lin >> 3;
        ntile = j % NT; j /= NT;
        const int mhi = j % 10;
        split = j / 10;
        mt = mhi * 8 + xcd;
        if (mt >= MT_) return;
    }
    const int m0 = mt * 64;
    const int n0 = ntile * BN;
    const int kb = split * KLEN;

    const int tid = threadIdx.x;
    const int lane = tid & 63;
    const int wid = tid >> 6;
    const int wm = wid >> 1;
    const int wn = wid & 1;

    if (MODE == 2 && tid < 64) {
        int r = m0 + tid, b = r / KSEL, t = sel[r];
        scv[tid] = scores[b * NTOK + t];
    }

    const int sr0 = tid >> 3;   // 0..31
    const int sc0 = tid & 7;    // 16B chunk

    s16x8 aR[2], bR[NFRAG];
    auto loadTile = [&](int k0) {            // k0 absolute (incl. kb), multiple of 64
        #pragma unroll
        for (int half = 0; half < 2; ++half) {
            int r = sr0 + half * 32;
            int k = k0 + sc0 * 8;
            if constexpr (MODE == 0) {
                aR[half] = *(const s16x8*)(A0 + (uint64_t)(m0 + r) * FLAT + k);
            } else if constexpr (MODE == 1) {
                aR[half] = *(const s16x8*)(A0 + (uint64_t)(m0 + r) * HID + k);
            } else if constexpr (MODE == 2) {
                if (k < D_) aR[half] = *(const s16x8*)(A0 + (uint64_t)(m0 + r) * D_ + k);
                else        aR[half] = *(const s16x8*)(A1 + (uint64_t)(m0 + r) * HID + (k - D_));
            } else {
                aR[half] = *(const s16x8*)(A0 + (uint64_t)(m0 + r) * 1536 + k);
            }
        }
        #pragma unroll
        for (int it = 0; it < NFRAG; ++it) {
            int r = it * 32 + sr0;
            int k = k0 + sc0 * 8;
            if constexpr (MODE == 0) {
                bR[it] = *(const s16x8*)(B0 + (uint64_t)(n0 + r) * FLAT + k);
            } else if constexpr (MODE == 1) {
                bR[it] = *(const s16x8*)(B0 + (uint64_t)(n0 + r) * HID + k);
            } else if constexpr (MODE == 2) {
                if (k < D_) bR[it] = *(const s16x8*)(B0 + (uint64_t)(n0 + r) * 1536 + k);
                else        bR[it] = *(const s16x8*)(B1 + (uint64_t)(n0 + r) * HID + (k - D_));
            } else {
                bR[it] = cvt8(Braw + (uint64_t)(n0 + r) * D_ + k);
            }
        }
    };
    auto writeTile = [&](int buf) {
        unsigned short* As = AsS + buf * 4096;
        unsigned short* Bs = BsS + buf * (BN * 64);
        #pragma unroll
        for (int half = 0; half < 2; ++half) {
            int r = sr0 + half * 32;
            int c = sc0 ^ (r & 7);                 // XOR swizzle (write side)
            *(s16x8*)&As[r * 64 + c * 8] = aR[half];
        }
        #pragma unroll
        for (int it = 0; it < NFRAG; ++it) {
            int r = it * 32 + sr0;
            int c = sc0 ^ (r & 7);
            *(s16x8*)&Bs[r * 64 + c * 8] = bR[it];
        }
    };

    f32x4 acc[2][NFRAG];
    #pragma unroll
    for (int i = 0; i < 2; ++i)
        #pragma unroll
        for (int jj = 0; jj < NFRAG; ++jj) acc[i][jj] = (f32x4){0.f, 0.f, 0.f, 0.f};

    loadTile(kb);
    writeTile(0);
    __syncthreads();
    if (NSTEP > 1) loadTile(kb + 64);

    int cur = 0;
    for (int t = 0; t < NSTEP; ++t) {
        const unsigned short* As = AsS + cur * 4096;
        const unsigned short* Bs = BsS + cur * (BN * 64);
        #pragma unroll
        for (int kk = 0; kk < 2; ++kk) {
            s16x8 af[2], bfr[NFRAG];
            #pragma unroll
            for (int i = 0; i < 2; ++i) {
                int row = wm * 32 + i * 16 + (lane & 15);
                int cch = (kk * 4 + (lane >> 4)) ^ (row & 7);   // XOR swizzle (read side)
                af[i] = *(const s16x8*)&As[row * 64 + cch * 8];
            }
            #pragma unroll
            for (int jj = 0; jj < NFRAG; ++jj) {
                int nrow = wn * (BN / 2) + jj * 16 + (lane & 15);
                int cch = (kk * 4 + (lane >> 4)) ^ (nrow & 7);
                bfr[jj] = *(const s16x8*)&Bs[nrow * 64 + cch * 8];
            }
            #pragma unroll
            for (int i = 0; i < 2; ++i)
                #pragma unroll
                for (int jj = 0; jj < NFRAG; ++jj)
                    acc[i][jj] = __builtin_amdgcn_mfma_f32_16x16x32_bf16(af[i], bfr[jj], acc[i][jj], 0, 0, 0);
        }
        if (t + 1 < NSTEP) {
            writeTile(cur ^ 1);
            __syncthreads();
            if (t + 2 < NSTEP) loadTile(kb + (t + 2) * 64);
            cur ^= 1;
        }
    }

    // epilogue: C row = (lane>>4)*4+reg, col = lane&15
    if constexpr (MODE == 2) {
        float wg2v[2] = { Wg2[n0 + wn * 32 + (lane & 15)],
                          Wg2[n0 + wn * 32 + 16 + (lane & 15)] };
        float psum[2][4];
        #pragma unroll
        for (int i = 0; i < 2; ++i)
            #pragma unroll
            for (int reg = 0; reg < 4; ++reg) psum[i][reg] = 0.f;
        #pragma unroll
        for (int i = 0; i < 2; ++i) {
            #pragma unroll
            for (int jj = 0; jj < 2; ++jj) {
                #pragma unroll
                for (int reg = 0; reg < 4; ++reg) {
                    int m = m0 + wm * 32 + i * 16 + (lane >> 4) * 4 + reg;
                    int n = n0 + wn * 32 + jj * 16 + (lane & 15);
                    float x = acc[i][jj][reg] + bias[n] + scv[m - m0] * WgLast[n];
                    x = x / (1.0f + __expf(-x));          // SiLU -> hg value
                    psum[i][reg] += x * wg2v[jj];
                }
            }
        }
        #pragma unroll
        for (int mask = 1; mask < 16; mask <<= 1)
            #pragma unroll
            for (int i = 0; i < 2; ++i)
                #pragma unroll
                for (int reg = 0; reg < 4; ++reg)
                    psum[i][reg] += __shfl_xor(psum[i][reg], mask);
        if ((lane & 15) == 0) {
            #pragma unroll
            for (int i = 0; i < 2; ++i)
                #pragma unroll
                for (int reg = 0; reg < 4; ++reg) {
                    int m = m0 + wm * 32 + i * 16 + (lane >> 4) * 4 + reg;
                    gpart[m * 12 + ntile * 2 + wn] = psum[i][reg];
                }
        }
        return;
    }
    #pragma unroll
    for (int i = 0; i < 2; ++i)
        #pragma unroll
        for (int jj = 0; jj < NFRAG; ++jj)
            #pragma unroll
            for (int reg = 0; reg < 4; ++reg) {
                int m = m0 + wm * 32 + i * 16 + (lane >> 4) * 4 + reg;
                int n = n0 + wn * (BN / 2) + jj * 16 + (lane & 15);
                if constexpr (MODE == 0) {
                    Pout[(uint64_t)split * PSTRIDE + (uint64_t)m * HID + n] = acc[i][jj][reg];
                } else if constexpr (MODE == 1) {
                    float x = acc[i][jj][reg] + bias[n];
                    ((unsigned short*)Cout)[(uint64_t)m * D_ + n] = f2bf(x);
                } else {  // MODE 3
                    ((unsigned short*)Cout)[(uint64_t)m * HID + n] = f2bf(acc[i][jj][reg]);
                }
            }
}

// ---------------- gworker: gather (blocks < MSEL) + Wfused/bias (36 blocks) ----------------
__global__ __launch_bounds__(256) void gworker_kernel(
    const int* __restrict__ sel, const float* __restrict__ highres,
    const float* __restrict__ base,
    unsigned short* __restrict__ Aloc, unsigned short* __restrict__ Abase,
    const unsigned short* __restrict__ Wg1t, const float* __restrict__ W2,
    const float* __restrict__ bg1, const float* __restrict__ b2,
    unsigned short* __restrict__ WF, float* __restrict__ bias_comb)
{
    __shared__ unsigned short AsS[2 * 4096];
    __shared__ unsigned short BsS[2 * 4096];
    const int bid = blockIdx.x;
    if (bid < MSEL) {
        const int r = bid;
        const int b = r / KSEL;
        const int t = sel[r];
        const int gy = t >> 5, gx = t & 31;
        for (int ch = threadIdx.x; ch < 480; ch += 256) {
            if (ch < 384) {
                int k8 = ch * 8;
                int p = k8 / D_;
                int col = k8 - p * D_;
                int hr = (gy * 2 + (p >> 1)) * 64 + gx * 2 + (p & 1);
                s16x8 v = cvt8(highres + ((uint64_t)b * NHR + hr) * D_ + col);
                *(s16x8*)(Aloc + (uint64_t)r * FLAT + k8) = v;
            } else {
                int col = (ch - 384) * 8;
                s16x8 v = cvt8(base + ((uint64_t)b * NTOK + t) * D_ + col);
                *(s16x8*)(Abase + (uint64_t)r * D_ + col) = v;
            }
        }
        return;
    }
    const int wb = bid - MSEL;               // 0..35
    gemm_body<3>(wb, Wg1t + 768, nullptr, nullptr, nullptr, W2, nullptr,
                 nullptr, nullptr, nullptr, nullptr, WF, nullptr, nullptr,
                 AsS, BsS, nullptr);
    if (wb % 6 == 0 && threadIdx.x < 64) {   // hh-tile 0 blocks: bias_comb for 64 n-rows
        int n = (wb / 6) * 64 + threadIdx.x;
        float s = bg1[n];
        const unsigned short* wr = Wg1t + (uint64_t)n * 1536 + 768;
        for (int d = 0; d < 768; ++d) s += b2[d] * bf2f(wr[d]);
        bias_comb[n] = s;
    }
}

// ---------------- gemm0: split-K=3 partials ----------------
__global__ __launch_bounds__(256) void gemm0_kernel(
    const unsigned short* __restrict__ Aloc, const unsigned short* __restrict__ W1t,
    float* __restrict__ Pout)
{
    __shared__ unsigned short AsS[2 * 4096];
    __shared__ unsigned short BsS[2 * 8192];
    gemm_body<0>(blockIdx.x, Aloc, nullptr, W1t, nullptr, nullptr, nullptr,
                 nullptr, nullptr, nullptr, nullptr, nullptr, Pout, nullptr,
                 AsS, BsS, nullptr);
}

// ---------------- combine: h = bf16(GELU(P0 + P1 + P2 + b1)) ----------------
__global__ __launch_bounds__(256) void combine_kernel(
    const float* __restrict__ P, const float* __restrict__ b1,
    unsigned short* __restrict__ h)
{
    const int idx = (blockIdx.x * 256 + threadIdx.x) * 8;   // < 4928*384, exact
    const int col = idx % HID;
    float4 a0 = *(const float4*)(P + idx),               a1 = *(const float4*)(P + idx + 4);
    float4 c0 = *(const float4*)(P + PSTRIDE + idx),     c1 = *(const float4*)(P + PSTRIDE + idx + 4);
    float4 d0 = *(const float4*)(P + 2 * PSTRIDE + idx), d1 = *(const float4*)(P + 2 * PSTRIDE + idx + 4);
    float4 bb0 = *(const float4*)(b1 + col), bb1 = *(const float4*)(b1 + col + 4);
    float xs[8] = { a0.x + c0.x + d0.x + bb0.x, a0.y + c0.y + d0.y + bb0.y,
                    a0.z + c0.z + d0.z + bb0.z, a0.w + c0.w + d0.w + bb0.w,
                    a1.x + c1.x + d1.x + bb1.x, a1.y + c1.y + d1.y + bb1.y,
                    a1.z + c1.z + d1.z + bb1.z, a1.w + c1.w + d1.w + bb1.w };
    u16x8 v;
    #pragma unroll
    for (int p = 0; p < 8; ++p) {
        float x = xs[p];
        x = 0.5f * x * (1.0f + erff(x * 0.70710678118654752f));
        v[p] = f2bf(x);
    }
    *(u16x8*)(h + idx) = v;
}

// ---------------- gemm12: fused rl-GEMM + gate-GEMM (independent, one dispatch) ----------------
__global__ __launch_bounds__(256) void gemm12_kernel(
    const unsigned short* __restrict__ h, const unsigned short* __restrict__ W2t,
    const float* __restrict__ b2,
    const unsigned short* __restrict__ Abase, const unsigned short* __restrict__ Wg1t,
    const unsigned short* __restrict__ WF, const float* __restrict__ bias_comb,
    const int* __restrict__ sel, const float* __restrict__ scores,
    const float* __restrict__ WgLast, const float* __restrict__ Wg2,
    unsigned short* __restrict__ rl, float* __restrict__ gpart)
{
    __shared__ unsigned short AsS[2 * 4096];
    __shared__ unsigned short BsS[2 * 8192];
    __shared__ float scv[64];
    if (blockIdx.x < 480) {
        gemm_body<1>(blockIdx.x, h, nullptr, W2t, nullptr, nullptr, b2,
                     nullptr, nullptr, nullptr, nullptr, rl, nullptr, nullptr,
                     AsS, BsS, nullptr);
    } else {
        gemm_body<2>(blockIdx.x - 480, Abase, h, Wg1t, WF, nullptr, bias_comb,
                     sel, scores, WgLast, Wg2, nullptr, nullptr, gpart,
                     AsS, BsS, scv);
    }
}

// ---------------- finalize: out = base, blended on selected rows ----------------
__global__ __launch_bounds__(256) void finalize_kernel(
    const int* __restrict__ rmap,
    const float* __restrict__ gpart, const float* __restrict__ bg2,
    const float* __restrict__ base, const unsigned short* __restrict__ rl,
    float* __restrict__ out)
{
    const int lane = threadIdx.x & 63;
    const int row = blockIdx.x * 4 + (threadIdx.x >> 6);
    const int rm = rmap[row];

    const uint64_t bo = (uint64_t)row * D_;
    const float4* b4 = (const float4*)(base + bo);
    float4* o4 = (float4*)(out + bo);

    if (rm < 0) {
        #pragma unroll
        for (int i = 0; i < 3; ++i) o4[lane + 64 * i] = b4[lane + 64 * i];
        return;
    }
    const float4* gp = (const float4*)(gpart + (uint64_t)rm * 12);
    float4 g0 = gp[0], g1 = gp[1], g2 = gp[2];
    float sum = g0.x + g0.y + g0.z + g0.w + g1.x + g1.y + g1.z + g1.w
              + g2.x + g2.y + g2.z + g2.w + bg2[0];
    float gate = 1.0f / (1.0f + __expf(-sum));

    const u16x4* r4 = (const u16x4*)(rl + (uint64_t)rm * D_);
    #pragma unroll
    for (int i = 0; i < 3; ++i) {
        int idx = lane + 64 * i;
        float4 bb = b4[idx];
        u16x4 rr = r4[idx];
        float4 oo;
        oo.x = bb.x + gate * (bf2f(rr[0]) - bb.x);
        oo.y = bb.y + gate * (bf2f(rr[1]) - bb.y);
        oo.z = bb.z + gate * (bf2f(rr[2]) - bb.z);
        oo.w = bb.w + gate * (bf2f(rr[3]) - bb.w);
        o4[idx] = oo;
    }
}

extern "C" void kernel_launch(void* const* d_in, const int* in_sizes, int n_in,
                              void* d_out, int out_size, void* d_ws, size_t ws_size,
                              hipStream_t stream) {
    const float* base   = (const float*)d_in[0];
    const float* hires  = (const float*)d_in[1];
    const float* scores = (const float*)d_in[2];
    const float* W1  = (const float*)d_in[3];
    const float* b1  = (const float*)d_in[4];
    const float* W2  = (const float*)d_in[5];
    const float* b2  = (const float*)d_in[6];
    const float* Wg1 = (const float*)d_in[7];
    const float* bg1 = (const float*)d_in[8];
    const float* Wg2 = (const float*)d_in[9];
    const float* bg2 = (const float*)d_in[10];
    float* out = (float*)d_out;

    char* ws = (char*)d_ws;
    int*            sel   = (int*)(ws + OFF_SEL);
    int*            rmap  = (int*)(ws + OFF_RMAP);
    float*          gpart = (float*)(ws + OFF_GPART);
    unsigned short* W1t   = (unsigned short*)(ws + OFF_W1T);
    unsigned short* W2t   = (unsigned short*)(ws + OFF_W2T);
    unsigned short* Wg1t  = (unsigned short*)(ws + OFF_WG1T);
    unsigned short* Abase = (unsigned short*)(ws + OFF_ABASE);
    unsigned short* h     = (unsigned short*)(ws + OFF_H);
    unsigned short* rl    = (unsigned short*)(ws + OFF_RL);
    unsigned short* WF    = (unsigned short*)(ws + OFF_WF);
    float*          bcomb = (float*)(ws + OFF_BC);
    unsigned short* Aloc  = (unsigned short*)d_out;             // scratch until finalize
    float*          P0    = (float*)((char*)d_out + DOUT_P0);

    prep_kernel<<<dim3(NB + 126), dim3(1024), 0, stream>>>(scores, sel, rmap,
                                                           W1, W2, Wg1, W1t, W2t, Wg1t);
    gworker_kernel<<<dim3(MSEL + 36), dim3(256), 0, stream>>>(
        sel, hires, base, Aloc, Abase, Wg1t, W2, bg1, b2, WF, bcomb);
    gemm0_kernel<<<dim3(8 * 10 * 3 * 3), dim3(256), 0, stream>>>(Aloc, W1t, P0);
    combine_kernel<<<dim3(924), dim3(256), 0, stream>>>(P0, b1, h);
    gemm12_kernel<<<dim3(480 + 480), dim3(256), 0, stream>>>(
        h, W2t, b2, Abase, Wg1t, WF, bcomb, sel, scores,
        Wg1 + (uint64_t)1536 * HID, Wg2, rl, gpart);
    finalize_kernel<<<dim3(NB * NTOK / 4), dim3(256), 0, stream>>>(rmap, gpart, bg2, base, rl, out);
}

// Round 13
// 148.473 us; speedup vs baseline: 1.1201x; 1.1201x over previous
//
#include <hip/hip_runtime.h>
#include <cstdint>

#define NB    32
#define NTOK  1024
#define D_    768
#define NHR   4096
#define HID   384
#define KSEL  154
#define MSEL  4928          // 32*154 = 77 * 64
#define MT_   77            // m-tiles of 64
#define FLAT  3072

typedef short  s16x8 __attribute__((ext_vector_type(8)));
typedef unsigned short u16x8 __attribute__((ext_vector_type(8)));
typedef unsigned short u16x4 __attribute__((ext_vector_type(4)));
typedef float  f32x4 __attribute__((ext_vector_type(4)));

__device__ inline unsigned short f2bf(float f) {
    uint32_t u = __builtin_bit_cast(uint32_t, f);
    u += 0x7FFFu + ((u >> 16) & 1u);          // RNE
    return (unsigned short)(u >> 16);
}
__device__ inline float bf2f(unsigned short h) {
    uint32_t u = ((uint32_t)h) << 16;
    return __builtin_bit_cast(float, u);
}
__device__ inline s16x8 cvt8(const float* __restrict__ p) {
    float4 v0 = *(const float4*)p, v1 = *(const float4*)(p + 4);
    s16x8 r;
    r[0]=(short)f2bf(v0.x); r[1]=(short)f2bf(v0.y); r[2]=(short)f2bf(v0.z); r[3]=(short)f2bf(v0.w);
    r[4]=(short)f2bf(v1.x); r[5]=(short)f2bf(v1.y); r[6]=(short)f2bf(v1.z); r[7]=(short)f2bf(v1.w);
    return r;
}

// ---- workspace layout (bytes) ----
#define OFF_SEL   0              // int[4928]
#define OFF_RMAP  32768          // int[32768]        131072
#define OFF_GPART 163840         // f32 [4928][12]    236544
#define OFF_W1T   401408         // bf16 [384][3072]  2359296
#define OFF_W2T   2760704        // bf16 [768][384]    589824
#define OFF_WG1T  3350528        // bf16 [384][1536]  1179648
#define OFF_ABASE 4530176        // bf16 [4928][768]  7569408
#define OFF_H     12099584       // bf16 [4928][384]  3784704
#define OFF_RL    15884288       // bf16 [4928][768]  7569408  (ends ~23.5 MB)
// ---- d_out scratch: Aloc bf16[4928][3072] at 0 (30.3 MB); P0/P1/P2 f32[4928][384]
//      partials after it — all consumed before finalize writes d_out.
#define DOUT_P0   32505856
#define PSTRIDE   (MSEL * HID)   // floats per split partial

// ---------------- prep: blocks 0-31 topk, blocks 32+ weight transpose+cvt ----------------
__global__ __launch_bounds__(1024) void prep_kernel(
    const float* __restrict__ scores, int* __restrict__ sel, int* __restrict__ rmap,
    const float* __restrict__ W1, const float* __restrict__ W2, const float* __restrict__ Wg1,
    unsigned short* __restrict__ W1t, unsigned short* __restrict__ W2t,
    unsigned short* __restrict__ Wg1t)
{
    __shared__ float s[NTOK];
    __shared__ int cnt;
    __shared__ unsigned short T[4][64][66];
    const int bid = blockIdx.x;
    if (bid < NB) {
        const int b = bid;
        const int t = threadIdx.x;
        s[t] = scores[b * NTOK + t];
        if (t == 0) cnt = 0;
        __syncthreads();
        float v = s[t];
        int rank = 0;
        for (int j = 0; j < NTOK; ++j) {
            float vj = s[j];
            rank += (vj > v) || (vj == v && j < t);
        }
        int rm = -1;
        if (rank < KSEL) {
            int pos = atomicAdd(&cnt, 1);
            rm = b * KSEL + pos;
            sel[rm] = t;
        }
        rmap[b * NTOK + t] = rm;
    } else {
        const int g = threadIdx.x >> 8;
        const int tid = threadIdx.x & 255;
        const int tile = (bid - NB) * 4 + g;     // 0..503
        const float* src; unsigned short* dst; int K, N, kt, nt;
        if (tile < 288)      { src = W1;  dst = W1t;  K = FLAT; N = HID; nt = tile % 6;  kt = tile / 6;  }
        else if (tile < 360) { int l = tile - 288; src = W2;  dst = W2t;  K = HID;  N = D_;  nt = l % 12; kt = l / 12; }
        else                 { int l = tile - 360; src = Wg1; dst = Wg1t; K = 1536; N = HID; nt = l % 6;  kt = l / 6;  }
        const int k0 = kt * 64, n0 = nt * 64;
        {
            const int ln = tid & 63, kc = tid >> 6;
            #pragma unroll
            for (int j = 0; j < 16; ++j)
                T[g][ln][kc * 16 + j] = f2bf(src[(uint64_t)(k0 + kc * 16 + j) * N + n0 + ln]);
        }
        __syncthreads();
        {
            const int row = tid >> 2, c0 = (tid & 3) * 16;
            u16x8 v0, v1;
            #pragma unroll
            for (int p = 0; p < 8; ++p) { v0[p] = T[g][row][c0 + p]; v1[p] = T[g][row][c0 + 8 + p]; }
            *(u16x8*)(dst + (uint64_t)(n0 + row) * K + k0 + c0) = v0;
            *(u16x8*)(dst + (uint64_t)(n0 + row) * K + k0 + c0 + 8) = v1;
        }
    }
}

// ---------------- gather selected rows -> bf16 Aloc (patches) + Abase ----------------
__global__ __launch_bounds__(256) void gather_kernel(
    const int* __restrict__ sel, const float* __restrict__ highres,
    const float* __restrict__ base,
    unsigned short* __restrict__ Aloc, unsigned short* __restrict__ Abase) {
    const int r = blockIdx.x;
    const int b = r / KSEL;
    const int t = sel[r];
    const int gy = t >> 5, gx = t & 31;
    for (int ch = threadIdx.x; ch < 480; ch += 256) {
        if (ch < 384) {
            int k8 = ch * 8;
            int p = k8 / D_;
            int col = k8 - p * D_;
            int hr = (gy * 2 + (p >> 1)) * 64 + gx * 2 + (p & 1);
            s16x8 v = cvt8(highres + ((uint64_t)b * NHR + hr) * D_ + col);
            *(s16x8*)(Aloc + (uint64_t)r * FLAT + k8) = v;
        } else {
            int col = (ch - 384) * 8;
            s16x8 v = cvt8(base + ((uint64_t)b * NTOK + t) * D_ + col);
            *(s16x8*)(Abase + (uint64_t)r * D_ + col) = v;
        }
    }
}

// ---------------- MFMA GEMM, XCD-grouped ----------------
// MODE 0: BM=64,BN=128, split-K=3: P[split] = Aloc @ W1t (f32 partials)
// MODE 1: BM=64,BN=128: rl = h @ W2t + b2 (bf16)
// MODE 2: BM=64,BN=64:  SiLU([Abase|rl] @ Wg1t + score*Wg1[1536] + bg1) -> gate partials
template <int MODE>
__global__ __launch_bounds__(256) void gemm_mfma(
    const unsigned short* __restrict__ A0,   // mode0: Aloc; mode1: h; mode2: Abase
    const unsigned short* __restrict__ A1,   // mode2: rl
    const unsigned short* __restrict__ Bt,
    const float* __restrict__ bias,
    const int* __restrict__ sel,
    const float* __restrict__ scores,
    const float* __restrict__ WgLast,
    const float* __restrict__ Wg2,
    void* __restrict__ Cout,
    float* __restrict__ Pout,
    float* __restrict__ gpart)
{
    constexpr int K = MODE == 0 ? FLAT : (MODE == 1 ? HID : 2 * D_);   // B row stride / logical K
    constexpr int N = MODE == 1 ? D_ : HID;
    constexpr int BN = (MODE == 2) ? 64 : 128;
    constexpr int NFRAG = BN / 32;            // frags per wave in n (2 or 4)
    constexpr int NT = N / BN;
    constexpr int KLEN = (MODE == 0) ? 1024 : K;
    constexpr int NSTEP = KLEN / 64;

    // XCD-grouping: same m-tile -> same XCD (lin%8)
    const int lin = blockIdx.x;
    const int xcd = lin & 7;
    int j = lin >> 3;
    const int ntile = j % NT; j /= NT;
    const int mhi = j % 10;
    const int split = j / 10;                 // < 3 for MODE 0
    const int mt = mhi * 8 + xcd;
    if (mt >= MT_) return;
    const int m0 = mt * 64;
    const int n0 = ntile * BN;
    const int kb = split * KLEN;

    __shared__ unsigned short As[2][64 * 64];
    __shared__ unsigned short Bs[2][BN * 64];
    __shared__ float scv[64];

    const int tid = threadIdx.x;
    const int lane = tid & 63;
    const int wid = tid >> 6;
    const int wm = wid >> 1;                  // 0..1: rows wm*32
    const int wn = wid & 1;                   // 0..1: cols wn*(BN/2)

    if (MODE == 2 && tid < 64) {
        int r = m0 + tid, b = r / KSEL, t = sel[r];
        scv[tid] = scores[b * NTOK + t];
    }
    if (MODE == 2) __syncthreads();

    const int sr0 = tid >> 3;   // 0..31
    const int sc0 = tid & 7;    // 16B chunk

    s16x8 aR[2], bR[NFRAG];
    auto loadTile = [&](int k0) {
        #pragma unroll
        for (int half = 0; half < 2; ++half) {
            int r = sr0 + half * 32;
            int k = k0 + sc0 * 8;
            const unsigned short* p;
            if (MODE == 0)      p = A0 + (uint64_t)(m0 + r) * FLAT + k;
            else if (MODE == 1) p = A0 + (uint64_t)(m0 + r) * HID + k;
            else {
                p = (k < D_) ? (A0 + (uint64_t)(m0 + r) * D_ + k)
                             : (A1 + (uint64_t)(m0 + r) * D_ + (k - D_));
            }
            aR[half] = *(const s16x8*)p;
        }
        #pragma unroll
        for (int it = 0; it < NFRAG; ++it) {
            int r = it * 32 + sr0;
            bR[it] = *(const s16x8*)(Bt + (uint64_t)(n0 + r) * K + k0 + sc0 * 8);
        }
    };
    auto writeTile = [&](int buf) {
        #pragma unroll
        for (int half = 0; half < 2; ++half) {
            int r = sr0 + half * 32;
            int c = sc0 ^ (r & 7);                 // XOR swizzle (write side)
            *(s16x8*)&As[buf][r * 64 + c * 8] = aR[half];
        }
        #pragma unroll
        for (int it = 0; it < NFRAG; ++it) {
            int r = it * 32 + sr0;
            int c = sc0 ^ (r & 7);
            *(s16x8*)&Bs[buf][r * 64 + c * 8] = bR[it];
        }
    };

    f32x4 acc[2][NFRAG];
    #pragma unroll
    for (int i = 0; i < 2; ++i)
        #pragma unroll
        for (int jj = 0; jj < NFRAG; ++jj) acc[i][jj] = (f32x4){0.f, 0.f, 0.f, 0.f};

    loadTile(kb);
    writeTile(0);
    __syncthreads();
    if (NSTEP > 1) loadTile(kb + 64);

    int cur = 0;
    for (int t = 0; t < NSTEP; ++t) {
        #pragma unroll
        for (int kk = 0; kk < 2; ++kk) {
            s16x8 af[2], bfr[NFRAG];
            #pragma unroll
            for (int i = 0; i < 2; ++i) {
                int row = wm * 32 + i * 16 + (lane & 15);
                int cch = (kk * 4 + (lane >> 4)) ^ (row & 7);   // XOR swizzle (read side)
                af[i] = *(const s16x8*)&As[cur][row * 64 + cch * 8];
            }
            #pragma unroll
            for (int jj = 0; jj < NFRAG; ++jj) {
                int nrow = wn * (BN / 2) + jj * 16 + (lane & 15);
                int cch = (kk * 4 + (lane >> 4)) ^ (nrow & 7);
                bfr[jj] = *(const s16x8*)&Bs[cur][nrow * 64 + cch * 8];
            }
            #pragma unroll
            for (int i = 0; i < 2; ++i)
                #pragma unroll
                for (int jj = 0; jj < NFRAG; ++jj)
                    acc[i][jj] = __builtin_amdgcn_mfma_f32_16x16x32_bf16(af[i], bfr[jj], acc[i][jj], 0, 0, 0);
        }
        if (t + 1 < NSTEP) {
            writeTile(cur ^ 1);
            __syncthreads();
            if (t + 2 < NSTEP) loadTile(kb + (t + 2) * 64);
            cur ^= 1;
        }
    }

    // epilogue: C row = (lane>>4)*4+reg, col = lane&15
    if (MODE == 2) {
        float wg2v[2] = { Wg2[n0 + wn * 32 + (lane & 15)],
                          Wg2[n0 + wn * 32 + 16 + (lane & 15)] };
        float psum[2][4];
        #pragma unroll
        for (int i = 0; i < 2; ++i)
            #pragma unroll
            for (int reg = 0; reg < 4; ++reg) psum[i][reg] = 0.f;
        #pragma unroll
        for (int i = 0; i < 2; ++i) {
            #pragma unroll
            for (int jj = 0; jj < 2; ++jj) {
                #pragma unroll
                for (int reg = 0; reg < 4; ++reg) {
                    int m = m0 + wm * 32 + i * 16 + (lane >> 4) * 4 + reg;
                    int n = n0 + wn * 32 + jj * 16 + (lane & 15);
                    float x = acc[i][jj][reg] + bias[n] + scv[m - m0] * WgLast[n];
                    x = x / (1.0f + __expf(-x));          // SiLU -> hg value
                    psum[i][reg] += x * wg2v[jj];
                }
            }
        }
        #pragma unroll
        for (int mask = 1; mask < 16; mask <<= 1)
            #pragma unroll
            for (int i = 0; i < 2; ++i)
                #pragma unroll
                for (int reg = 0; reg < 4; ++reg)
                    psum[i][reg] += __shfl_xor(psum[i][reg], mask);
        if ((lane & 15) == 0) {
            #pragma unroll
            for (int i = 0; i < 2; ++i)
                #pragma unroll
                for (int reg = 0; reg < 4; ++reg) {
                    int m = m0 + wm * 32 + i * 16 + (lane >> 4) * 4 + reg;
                    gpart[m * 12 + ntile * 2 + wn] = psum[i][reg];
                }
        }
        return;
    }
    float* P = (MODE == 0) ? (Pout + (uint64_t)split * PSTRIDE) : nullptr;
    #pragma unroll
    for (int i = 0; i < 2; ++i)
        #pragma unroll
        for (int jj = 0; jj < NFRAG; ++jj)
            #pragma unroll
            for (int reg = 0; reg < 4; ++reg) {
                int m = m0 + wm * 32 + i * 16 + (lane >> 4) * 4 + reg;
                int n = n0 + wn * (BN / 2) + jj * 16 + (lane & 15);
                if (MODE == 0) {
                    P[(uint64_t)m * HID + n] = acc[i][jj][reg];   // raw partial
                } else {
                    float x = acc[i][jj][reg] + bias[n];
                    ((unsigned short*)Cout)[(uint64_t)m * D_ + n] = f2bf(x);
                }
            }
}

// ---------------- combine: h = bf16(GELU(P0 + P1 + P2 + b1)) ----------------
__global__ __launch_bounds__(256) void combine_kernel(
    const float* __restrict__ P, const float* __restrict__ b1,
    unsigned short* __restrict__ h)
{
    const int idx = (blockIdx.x * 256 + threadIdx.x) * 8;   // < 4928*384, exact
    const int col = idx % HID;
    float4 a0 = *(const float4*)(P + idx),               a1 = *(const float4*)(P + idx + 4);
    float4 c0 = *(const float4*)(P + PSTRIDE + idx),     c1 = *(const float4*)(P + PSTRIDE + idx + 4);
    float4 d0 = *(const float4*)(P + 2 * PSTRIDE + idx), d1 = *(const float4*)(P + 2 * PSTRIDE + idx + 4);
    float4 bb0 = *(const float4*)(b1 + col), bb1 = *(const float4*)(b1 + col + 4);
    float xs[8] = { a0.x + c0.x + d0.x + bb0.x, a0.y + c0.y + d0.y + bb0.y,
                    a0.z + c0.z + d0.z + bb0.z, a0.w + c0.w + d0.w + bb0.w,
                    a1.x + c1.x + d1.x + bb1.x, a1.y + c1.y + d1.y + bb1.y,
                    a1.z + c1.z + d1.z + bb1.z, a1.w + c1.w + d1.w + bb1.w };
    u16x8 v;
    #pragma unroll
    for (int p = 0; p < 8; ++p) {
        float x = xs[p];
        x = 0.5f * x * (1.0f + erff(x * 0.70710678118654752f));
        v[p] = f2bf(x);
    }
    *(u16x8*)(h + idx) = v;
}

// ---------------- finalize: out = base, blended on selected rows ----------------
__global__ __launch_bounds__(256) void finalize_kernel(
    const int* __restrict__ rmap,
    const float* __restrict__ gpart, const float* __restrict__ bg2,
    const float* __restrict__ base, const unsigned short* __restrict__ rl,
    float* __restrict__ out)
{
    const int lane = threadIdx.x & 63;
    const int row = blockIdx.x * 4 + (threadIdx.x >> 6);
    const int rm = rmap[row];

    const uint64_t bo = (uint64_t)row * D_;
    const float4* b4 = (const float4*)(base + bo);
    float4* o4 = (float4*)(out + bo);

    if (rm < 0) {
        #pragma unroll
        for (int i = 0; i < 3; ++i) o4[lane + 64 * i] = b4[lane + 64 * i];
        return;
    }
    const float4* gp = (const float4*)(gpart + (uint64_t)rm * 12);
    float4 g0 = gp[0], g1 = gp[1], g2 = gp[2];
    float sum = g0.x + g0.y + g0.z + g0.w + g1.x + g1.y + g1.z + g1.w
              + g2.x + g2.y + g2.z + g2.w + bg2[0];
    float gate = 1.0f / (1.0f + __expf(-sum));

    const u16x4* r4 = (const u16x4*)(rl + (uint64_t)rm * D_);
    #pragma unroll
    for (int i = 0; i < 3; ++i) {
        int idx = lane + 64 * i;
        float4 bb = b4[idx];
        u16x4 rr = r4[idx];
        float4 oo;
        oo.x = bb.x + gate * (bf2f(rr[0]) - bb.x);
        oo.y = bb.y + gate * (bf2f(rr[1]) - bb.y);
        oo.z = bb.z + gate * (bf2f(rr[2]) - bb.z);
        oo.w = bb.w + gate * (bf2f(rr[3]) - bb.w);
        o4[idx] = oo;
    }
}

extern "C" void kernel_launch(void* const* d_in, const int* in_sizes, int n_in,
                              void* d_out, int out_size, void* d_ws, size_t ws_size,
                              hipStream_t stream) {
    const float* base   = (const float*)d_in[0];
    const float* hires  = (const float*)d_in[1];
    const float* scores = (const float*)d_in[2];
    const float* W1  = (const float*)d_in[3];
    const float* b1  = (const float*)d_in[4];
    const float* W2  = (const float*)d_in[5];
    const float* b2  = (const float*)d_in[6];
    const float* Wg1 = (const float*)d_in[7];
    const float* bg1 = (const float*)d_in[8];
    const float* Wg2 = (const float*)d_in[9];
    const float* bg2 = (const float*)d_in[10];
    float* out = (float*)d_out;

    char* ws = (char*)d_ws;
    int*            sel   = (int*)(ws + OFF_SEL);
    int*            rmap  = (int*)(ws + OFF_RMAP);
    float*          gpart = (float*)(ws + OFF_GPART);
    unsigned short* W1t   = (unsigned short*)(ws + OFF_W1T);
    unsigned short* W2t   = (unsigned short*)(ws + OFF_W2T);
    unsigned short* Wg1t  = (unsigned short*)(ws + OFF_WG1T);
    unsigned short* Abase = (unsigned short*)(ws + OFF_ABASE);
    unsigned short* h     = (unsigned short*)(ws + OFF_H);
    unsigned short* rl    = (unsigned short*)(ws + OFF_RL);
    unsigned short* Aloc  = (unsigned short*)d_out;             // scratch until finalize
    float*          P0    = (float*)((char*)d_out + DOUT_P0);

    prep_kernel<<<dim3(NB + 126), dim3(1024), 0, stream>>>(scores, sel, rmap,
                                                           W1, W2, Wg1, W1t, W2t, Wg1t);
    gather_kernel<<<dim3(MSEL), dim3(256), 0, stream>>>(sel, hires, base, Aloc, Abase);
    gemm_mfma<0><<<dim3(8 * 10 * 3 * 3), dim3(256), 0, stream>>>(
        Aloc, nullptr, W1t, nullptr, nullptr, nullptr, nullptr, nullptr, nullptr, P0, nullptr);
    combine_kernel<<<dim3(924), dim3(256), 0, stream>>>(P0, b1, h);
    gemm_mfma<1><<<dim3(8 * 10 * 6), dim3(256), 0, stream>>>(
        h, nullptr, W2t, b2, nullptr, nullptr, nullptr, nullptr, rl, nullptr, nullptr);
    gemm_mfma<2><<<dim3(8 * 10 * 6), dim3(256), 0, stream>>>(
        Abase, rl, Wg1t, bg1, sel, scores, Wg1 + (uint64_t)1536 * HID, Wg2,
        nullptr, nullptr, gpart);
    finalize_kernel<<<dim3(NB * NTOK / 4), dim3(256), 0, stream>>>(rmap, gpart, bg2, base, rl, out);
}